// Round 1
// baseline (307.473 us; speedup 1.0000x reference)
//
#include <hip/hip_runtime.h>
#include <math.h>

#define IMG_H 512
#define IMG_W 512
#define NPLANES 48            // 16 * 3
#define RAD 5
#define TAPS 11
#define CHUNK 33              // multiple of 11 -> static ring phase after unroll
#define STRIP 64              // columns per wave (one autonomous wave per strip)
#define SBUF 80               // 74 used (64 + 2*RAD), padded
#define ROWB (IMG_W * 4)      // row stride, bytes
#define PLANEB (IMG_H * IMG_W * 4)

typedef float v2f __attribute__((ext_vector_type(2)));
typedef int   v4i __attribute__((ext_vector_type(4)));

// Raw buffer load with HARDWARE bounds check: SRD num_records = plane bytes,
// so any voffset outside [0, PLANEB) returns 0.0f with no memory traffic.
// This replaces ALL per-row software bounds logic (row <0 / >=512, col <0):
//  - negative row     -> voffset very negative -> huge unsigned -> OOB -> 0
//  - row >= 512       -> voffset >= PLANEB -> OOB -> 0 (never reads next plane)
//  - col < 0 (lane)   -> poisoned once at setup (row-invariant), stays OOB
//  - tail col >= 512 / lane >= 10 -> poisoned once at setup, stays OOB
__device__ float
llvm_amdgcn_raw_buffer_load_f32(v4i srsrc, int voffset, int soffset, int aux)
    __asm("llvm.amdgcn.raw.buffer.load.f32");

#define WAVE_FENCE_WAR()  __asm__ __volatile__("" ::: "memory")
#define WAVE_FENCE_RAW()  __asm__ __volatile__("s_waitcnt lgkmcnt(0)" ::: "memory")

struct GaussW { float w[TAPS]; };

// Structure notes (evidence-driven):
//  - R2: __launch_bounds__(256,6) capped VGPR -> 55-float ring spilled,
//    WRITE_SIZE 24KB->291MB, 350us. Ring needs ~80 VGPRs; (256,5) caps at
//    ~102 -> safe, and raises residency 16 -> 20 waves/CU (occupancy was
//    pinned at the (256,4) cap: measured 45% vs 50% cap).
//  - R5: one wave per 64-col strip, no block barriers. R6: packed fp32.
//  - R7 (this): SRD hardware-OOB loads kill per-row bounds/address VALU
//    (per row: 4 buffer_load + 2 v_add_u32, nothing else); finalize folded
//    into last block (saves one launch). WRITE_SIZE is the spill tripwire.
__global__ __launch_bounds__(256, 5)
void ssim_main(const float* __restrict__ img1, const float* __restrict__ img2,
               double* __restrict__ sum_ws, float* __restrict__ out, GaussW gw) {
    __shared__ float2 srow[4][SBUF];   // one private (a,b) row buffer per wave
    __shared__ float wsum[4];

    const int tid  = threadIdx.x;
    const int wid  = tid >> 6;         // wave id 0..3
    const int lane = tid & 63;
    const int c0   = blockIdx.x * (4 * STRIP) + wid * STRIP;  // strip base col
    const int y0   = blockIdx.y * CHUNK;
    const size_t pbase = (size_t)blockIdx.z * (IMG_H * IMG_W);
    float2* buf = srow[wid];

    // Per-plane SRDs (wave-uniform -> SGPRs). word1[15:0]=base[47:32] (device
    // VAs fit 48 bits, stride field zero); word2=num_records bytes; word3=raw.
    v4i srd1, srd2;
    {
        union { const float* p; int w[2]; } u;
        u.p = img1 + pbase; srd1 = (v4i){u.w[0], u.w[1], PLANEB, 0x00020000};
        u.p = img2 + pbase; srd2 = (v4i){u.w[0], u.w[1], PLANEB, 0x00020000};
    }

    // Row-invariant voffsets; per row just += ROWB. int arithmetic wraps mod
    // 2^32 so negative (OOB) prologue offsets advance into valid range exactly
    // when the row becomes valid.
    const int colm = c0 - RAD + lane;              // buf idx = lane
    int vo = (y0 - RAD) * ROWB + colm * 4;
    if (colm < 0) vo = 0x40000000;                 // col<0 aliases prev row: poison
    const int c2 = c0 + STRIP - RAD + lane;        // buf idx = 64+lane (lane<10)
    int vt = (y0 - RAD) * ROWB + c2 * 4;
    if (lane >= 2 * RAD || c2 >= IMG_W) vt = 0x40000000;  // stays OOB all 44 rows

    // register ring, 11 rows deep:
    //   rab = (conv_h(a), conv_h(b)), rsq = (conv_h(a^2), conv_h(b^2)), rx = conv_h(ab)
    v2f rab[TAPS], rsq[TAPS];
    float rx[TAPS];

    float pa, pb, pta, ptb;            // prefetch registers for the next row

    auto load_regs = [&]() {
        pa  = llvm_amdgcn_raw_buffer_load_f32(srd1, vo, 0, 0);
        pb  = llvm_amdgcn_raw_buffer_load_f32(srd2, vo, 0, 0);
        pta = llvm_amdgcn_raw_buffer_load_f32(srd1, vt, 0, 0);
        ptb = llvm_amdgcn_raw_buffer_load_f32(srd2, vt, 0, 0);
        vo += ROWB; vt += ROWB;
    };

    auto store_lds = [&]() {
        WAVE_FENCE_WAR();              // don't sink writes above prior reads
        buf[lane] = make_float2(pa, pb);
        if (lane < 2 * RAD) buf[STRIP + lane] = make_float2(pta, ptb);
        WAVE_FENCE_RAW();              // don't hoist following reads above it
    };

    // packed horizontal conv: per tap 1 pk_mul + 1 mul + 2 pk_fma + 1 fma.
    // No row guard needed: OOB rows stored zeros -> contribute w*0 (exact).
    auto hconv = [&](v2f& oab, v2f& osq, float& ox) {
        v2f aab = {0.f, 0.f}, asq = {0.f, 0.f};
        float ax = 0.f;
        #pragma unroll
        for (int d = 0; d < TAPS; ++d) {
            v2f v = *(const v2f*)&buf[lane + d];   // (a, b)
            float w = gw.w[d];
            v2f wv = {w, w};
            aab = __builtin_elementwise_fma(wv, v, aab);          // pk_fma
            v2f sq = v * v;                                       // pk_mul
            asq = __builtin_elementwise_fma(wv, sq, asq);         // pk_fma
            ax  = fmaf(w, v.x * v.y, ax);                         // mul+fma
        }
        oab = aab; osq = asq; ox = ax;
    };

    // ---- prologue: h-rows for global rows y0-5 .. y0+4 -> ring slots 0..9
    load_regs();
    #pragma unroll
    for (int k = 0; k < TAPS - 1; ++k) {
        store_lds();
        load_regs();                   // next row's loads in flight during hconv
        hconv(rab[k], rsq[k], rx[k]);
    }

    const float C1v = 0.0001f;  // 0.01^2
    const float C2v = 0.0009f;  // 0.03^2
    float acc = 0.f;

    // ---- main: CHUNK output rows, unrolled by 11 so ring indices are static
    for (int kk = 0; kk < CHUNK; kk += TAPS) {
        #pragma unroll
        for (int j = 0; j < TAPS; ++j) {
            store_lds();               // publish prefetched row
            load_regs();               // issue next row's loads NOW
            hconv(rab[(j + 10) % TAPS], rsq[(j + 10) % TAPS], rx[(j + 10) % TAPS]);

            const int y = y0 + kk + j; // output row
            if (y < IMG_H) {
                // packed vertical conv: per tap 2 pk_fma + 1 fma
                v2f mu = {0.f, 0.f}, s2 = {0.f, 0.f};
                float sx = 0.f;
                #pragma unroll
                for (int t = 0; t < TAPS; ++t) {
                    const int s = (j + t) % TAPS;  // static after unroll
                    float w = gw.w[t];
                    v2f wv = {w, w};
                    mu = __builtin_elementwise_fma(wv, rab[s], mu);
                    s2 = __builtin_elementwise_fma(wv, rsq[s], s2);
                    sx = fmaf(w, rx[s], sx);
                }
                float mu1 = mu.x, mu2 = mu.y;
                float mu1sq = mu1 * mu1, mu2sq = mu2 * mu2, mu12 = mu1 * mu2;
                float sg1 = s2.x - mu1sq, sg2 = s2.y - mu2sq, sg12 = sx - mu12;
                float num = (2.f * mu12 + C1v) * (2.f * sg12 + C2v);
                float den = (mu1sq + mu2sq + C1v) * (sg1 + sg2 + C2v);
                acc += num * __builtin_amdgcn_rcpf(den);
            }
        }
    }

    // wave (64-lane) shuffle reduce -> block partials -> one atomic per block
    #pragma unroll
    for (int off = 32; off > 0; off >>= 1) acc += __shfl_down(acc, off, 64);
    if (lane == 0) wsum[wid] = acc;
    __syncthreads();                   // only block barrier in the kernel
    if (tid == 0) {
        double s = (double)wsum[0] + (double)wsum[1] + (double)wsum[2] + (double)wsum[3];
        atomicAdd(sum_ws, s);
        // last block finalizes: device-scope atomics + fences (XCD-safe)
        __threadfence();
        unsigned* ctr = (unsigned*)(sum_ws + 1);
        unsigned nb = gridDim.x * gridDim.y * gridDim.z;
        if (atomicAdd(ctr, 1u) == nb - 1u) {
            __threadfence();
            double total = atomicAdd(sum_ws, 0.0);   // coherent read of final sum
            out[0] = (float)(total * (1.0 / (16.0 * 3.0 * 512.0 * 512.0)));
        }
    }
}

extern "C" void kernel_launch(void* const* d_in, const int* in_sizes, int n_in,
                              void* d_out, int out_size, void* d_ws, size_t ws_size,
                              hipStream_t stream) {
    const float* img1 = (const float*)d_in[0];
    const float* img2 = (const float*)d_in[1];
    float* out = (float*)d_out;
    double* ws = (double*)d_ws;

    // d_ws poisoned 0xAA before every launch — zero accumulator + done-counter
    hipMemsetAsync(ws, 0, 2 * sizeof(double), stream);

    // Gaussian weights computed on host in double, passed via kernarg (SGPRs)
    GaussW gw;
    double g[TAPS], s = 0.0;
    for (int i = 0; i < TAPS; ++i) {
        double x = (double)(i - TAPS / 2);
        g[i] = exp(-(x * x) / (2.0 * 1.5 * 1.5));
        s += g[i];
    }
    for (int i = 0; i < TAPS; ++i) gw.w[i] = (float)(g[i] / s);

    // 2 x 16 x 48 = 1536 blocks; each block = 4 autonomous 64-col wave strips
    dim3 grid(IMG_W / (4 * STRIP), (IMG_H + CHUNK - 1) / CHUNK, NPLANES);
    ssim_main<<<grid, 256, 0, stream>>>(img1, img2, ws, out, gw);
}